// Round 2
// baseline (440.287 us; speedup 1.0000x reference)
//
#include <hip/hip_runtime.h>
#include <math.h>

#define B_   256
#define V_   6890
#define NJ_  24
#define NB_  10
#define NP_  207
#define NJR_ 43
#define V3_  20670   // V*3
#define NK_  217     // NB + NP

// ws layout (floats)
#define JST_OFF 0        // 24*33 = 792
#define CG_OFF  1024     // coefG: 217*256 = 55552  (rows 0..9 beta, 10..216 pose_feature)
#define A_OFF   57344    // 256*24*12 = 73728

// ---------------------------------------------------------------------------
// K0: Jst[j][0..2] = sum_v JR[j,v]*v_template[v,d]
//     Jst[j][3+k*3+d] = sum_v JR[j,v]*shapedirs[k, v*3+d]
// ---------------------------------------------------------------------------
__global__ __launch_bounds__(256) void k_jst(const float* __restrict__ JR,
                                             const float* __restrict__ vtm,
                                             const float* __restrict__ sd,
                                             float* __restrict__ Jst)
{
    const int j = blockIdx.x;
    const int tid = threadIdx.x;
    float acc[33];
#pragma unroll
    for (int c = 0; c < 33; c++) acc[c] = 0.f;

    for (int v = tid; v < V_; v += 256) {
        float jr = JR[(size_t)j * V_ + v];
        const float* tv = vtm + (size_t)v * 3;
        acc[0] += jr * tv[0];
        acc[1] += jr * tv[1];
        acc[2] += jr * tv[2];
#pragma unroll
        for (int k = 0; k < 10; k++) {
            const float* sp = sd + (size_t)k * V3_ + (size_t)v * 3;
            acc[3 + k*3 + 0] += jr * sp[0];
            acc[3 + k*3 + 1] += jr * sp[1];
            acc[3 + k*3 + 2] += jr * sp[2];
        }
    }
#pragma unroll
    for (int c = 0; c < 33; c++) {
        float s = acc[c];
#pragma unroll
        for (int off = 32; off > 0; off >>= 1) s += __shfl_xor(s, off);
        acc[c] = s;
    }
    __shared__ float red[4][33];
    const int wv = tid >> 6, ln = tid & 63;
    if (ln == 0) {
#pragma unroll
        for (int c = 0; c < 33; c++) red[wv][c] = acc[c];
    }
    __syncthreads();
    if (tid < 33)
        Jst[j * 33 + tid] = red[0][tid] + red[1][tid] + red[2][tid] + red[3][tid];
}

// ---------------------------------------------------------------------------
// K1: rodrigues + kinematic chain.  Writes coefG (transposed coeffs) and A.
// ---------------------------------------------------------------------------
__global__ void k_chain(const float* __restrict__ beta,
                        const float* __restrict__ theta,
                        const float* __restrict__ Jst,
                        float* __restrict__ coefG,
                        float* __restrict__ Aout)
{
    __shared__ float resL[24 * 12 * 32];
    __shared__ float JL[24 * 3 * 32];
    const int t = threadIdx.x;            // 0..31
    const int b = blockIdx.x * 32 + t;

    float bet[10];
#pragma unroll
    for (int k = 0; k < 10; k++) bet[k] = beta[b * 10 + k];
#pragma unroll
    for (int k = 0; k < 10; k++) coefG[k * 256 + b] = bet[k];   // coalesced per block

#pragma unroll
    for (int j = 0; j < 24; j++) {
#pragma unroll
        for (int d = 0; d < 3; d++) {
            float s = Jst[j * 33 + d];
#pragma unroll
            for (int k = 0; k < 10; k++) s += bet[k] * Jst[j * 33 + 3 + k * 3 + d];
            JL[(j * 3 + d) * 32 + t] = s;
        }
    }

    const int par[24] = {0,0,0,0,1,2,3,4,5,6,7,8,9,9,9,12,13,14,16,17,18,19,20,21};

#pragma unroll
    for (int j = 0; j < 24; j++) {
        float t0 = theta[b * 72 + 3 * j + 0];
        float t1 = theta[b * 72 + 3 * j + 1];
        float t2 = theta[b * 72 + 3 * j + 2];
        float e0 = t0 + 1e-8f, e1 = t1 + 1e-8f, e2 = t2 + 1e-8f;
        float ang = sqrtf(e0 * e0 + e1 * e1 + e2 * e2);
        float inva = 1.0f / ang;
        float r0 = t0 * inva, r1 = t1 * inva, r2 = t2 * inva;
        float h = 0.5f * ang;
        float qw = cosf(h), sh = sinf(h);
        float qx = sh * r0, qy = sh * r1, qz = sh * r2;
        float qn = sqrtf(qw * qw + qx * qx + qy * qy + qz * qz);
        float inq = 1.0f / qn;
        qw *= inq; qx *= inq; qy *= inq; qz *= inq;
        float R[9];
        R[0] = 1.f - 2.f * (qy * qy + qz * qz);
        R[1] = 2.f * (qx * qy - qw * qz);
        R[2] = 2.f * (qx * qz + qw * qy);
        R[3] = 2.f * (qx * qy + qw * qz);
        R[4] = 1.f - 2.f * (qx * qx + qz * qz);
        R[5] = 2.f * (qy * qz - qw * qx);
        R[6] = 2.f * (qx * qz - qw * qy);
        R[7] = 2.f * (qy * qz + qw * qx);
        R[8] = 1.f - 2.f * (qx * qx + qy * qy);

        if (j == 0) {
#pragma unroll
            for (int m = 0; m < 3; m++) {
                resL[(0 * 12 + m * 4 + 0) * 32 + t] = R[m * 3 + 0];
                resL[(0 * 12 + m * 4 + 1) * 32 + t] = -R[m * 3 + 1];
                resL[(0 * 12 + m * 4 + 2) * 32 + t] = -R[m * 3 + 2];
                resL[(0 * 12 + m * 4 + 3) * 32 + t] = JL[(0 * 3 + m) * 32 + t];
            }
        } else {
#pragma unroll
            for (int e = 0; e < 9; e++)
                coefG[(10 + (j - 1) * 9 + e) * 256 + b] =
                    R[e] - ((e == 0 || e == 4 || e == 8) ? 1.f : 0.f);
            const int p = par[j];
            float tx = JL[(j * 3 + 0) * 32 + t] - JL[(p * 3 + 0) * 32 + t];
            float ty = JL[(j * 3 + 1) * 32 + t] - JL[(p * 3 + 1) * 32 + t];
            float tz = JL[(j * 3 + 2) * 32 + t] - JL[(p * 3 + 2) * 32 + t];
#pragma unroll
            for (int m = 0; m < 3; m++) {
                float pm0 = resL[(p * 12 + m * 4 + 0) * 32 + t];
                float pm1 = resL[(p * 12 + m * 4 + 1) * 32 + t];
                float pm2 = resL[(p * 12 + m * 4 + 2) * 32 + t];
                float pm3 = resL[(p * 12 + m * 4 + 3) * 32 + t];
                resL[(j * 12 + m * 4 + 0) * 32 + t] = pm0 * R[0] + pm1 * R[3] + pm2 * R[6];
                resL[(j * 12 + m * 4 + 1) * 32 + t] = pm0 * R[1] + pm1 * R[4] + pm2 * R[7];
                resL[(j * 12 + m * 4 + 2) * 32 + t] = pm0 * R[2] + pm1 * R[5] + pm2 * R[8];
                resL[(j * 12 + m * 4 + 3) * 32 + t] = pm0 * tx + pm1 * ty + pm2 * tz + pm3;
            }
        }
    }

#pragma unroll
    for (int j = 0; j < 24; j++) {
        float Jx = JL[(j * 3 + 0) * 32 + t];
        float Jy = JL[(j * 3 + 1) * 32 + t];
        float Jz = JL[(j * 3 + 2) * 32 + t];
#pragma unroll
        for (int m = 0; m < 3; m++) {
            float c0 = resL[(j * 12 + m * 4 + 0) * 32 + t];
            float c1 = resL[(j * 12 + m * 4 + 1) * 32 + t];
            float c2 = resL[(j * 12 + m * 4 + 2) * 32 + t];
            float c3 = resL[(j * 12 + m * 4 + 3) * 32 + t];
            float* ap = Aout + (size_t)(b * 24 + j) * 12 + m * 4;
            ap[0] = c0; ap[1] = c1; ap[2] = c2;
            ap[3] = c3 - (c0 * Jx + c1 * Jy + c2 * Jz);
        }
    }
}

// ---------------------------------------------------------------------------
// K2: v_posed GEMM.  Block = 32 batches x 128 cols; thread = 4b x 4c.
// coefG pre-transposed -> coalesced staging.  LDS 27.8 KB -> 5 blocks/CU.
// Explicit one-row prefetch; no temp arrays (no spill risk).
// ---------------------------------------------------------------------------
__global__ __launch_bounds__(256) void k_vposed(const float* __restrict__ cg,
                                                const float* __restrict__ vt,
                                                const float* __restrict__ sd,
                                                const float* __restrict__ pd,
                                                float* __restrict__ vp)
{
    __shared__ __align__(16) float coefT[NK_ * 32];  // [k][bb]
    const int tid = threadIdx.x;
    const int bblk = blockIdx.y * 32;
    for (int idx = tid; idx < NK_ * 32; idx += 256)
        coefT[idx] = cg[(idx >> 5) * 256 + bblk + (idx & 31)];
    __syncthreads();

    const int tx = tid & 31, ty = tid >> 5;     // ty: 8 groups of 4 batches
    int ibase = blockIdx.x * 128 + tx * 4;
    if (ibase > V3_ - 4) ibase = V3_ - 4;       // tail clamp (duplicate writes benign)

    float acc[4][4];
#pragma unroll
    for (int i = 0; i < 4; i++)
#pragma unroll
        for (int q = 0; q < 4; q++) acc[i][q] = 0.f;

    // prefetch row 0
    float2 dA = *(const float2*)(sd + ibase);
    float2 dB = *(const float2*)(sd + ibase + 2);

#pragma unroll 4
    for (int k = 0; k < NK_; k++) {
        float2 cA = dA, cB = dB;
        int kn = (k + 1 < NK_) ? k + 1 : NK_ - 1;
        const float* nxt = (kn < 10) ? (sd + (size_t)kn * V3_ + ibase)
                                     : (pd + (size_t)(kn - 10) * V3_ + ibase);
        dA = *(const float2*)nxt;
        dB = *(const float2*)(nxt + 2);

        const float4 c4 = *(const float4*)(coefT + k * 32 + ty * 4);  // b128, 2-way bcast
        acc[0][0] += c4.x * cA.x; acc[0][1] += c4.x * cA.y;
        acc[0][2] += c4.x * cB.x; acc[0][3] += c4.x * cB.y;
        acc[1][0] += c4.y * cA.x; acc[1][1] += c4.y * cA.y;
        acc[1][2] += c4.y * cB.x; acc[1][3] += c4.y * cB.y;
        acc[2][0] += c4.z * cA.x; acc[2][1] += c4.z * cA.y;
        acc[2][2] += c4.z * cB.x; acc[2][3] += c4.z * cB.y;
        acc[3][0] += c4.w * cA.x; acc[3][1] += c4.w * cA.y;
        acc[3][2] += c4.w * cB.x; acc[3][3] += c4.w * cB.y;
    }

    float2 vA = *(const float2*)(vt + ibase);
    float2 vB = *(const float2*)(vt + ibase + 2);
#pragma unroll
    for (int i = 0; i < 4; i++) {
        int b = bblk + ty * 4 + i;
        float* o = vp + (size_t)b * V3_ + ibase;
        float2 o0 = {acc[i][0] + vA.x, acc[i][1] + vA.y};
        float2 o1 = {acc[i][2] + vB.x, acc[i][3] + vB.y};
        *(float2*)o = o0;
        *(float2*)(o + 2) = o1;
    }
}

// ---------------------------------------------------------------------------
// K3: skinning, in place in d_out.  weights batch-broadcast -> slice [0].
// ---------------------------------------------------------------------------
__global__ __launch_bounds__(256) void k_skin(const float* __restrict__ w0,
                                              const float* __restrict__ A,
                                              float* __restrict__ verts)
{
    __shared__ __align__(16) float AL[288];
    const int tid = threadIdx.x;
    const int b = blockIdx.y;
    for (int i = tid; i < 288; i += 256) AL[i] = A[(size_t)b * 288 + i];
    __syncthreads();

#pragma unroll
    for (int rep = 0; rep < 2; rep++) {
        int v = blockIdx.x * 512 + rep * 256 + tid;
        if (v >= V_) continue;
        float wr[24];
        const float4* wp = (const float4*)(w0 + (size_t)v * 24);
#pragma unroll
        for (int q = 0; q < 6; q++) {
            float4 f = wp[q];
            wr[q * 4 + 0] = f.x; wr[q * 4 + 1] = f.y;
            wr[q * 4 + 2] = f.z; wr[q * 4 + 3] = f.w;
        }
        float T[12];
#pragma unroll
        for (int e = 0; e < 12; e++) T[e] = 0.f;
#pragma unroll
        for (int j = 0; j < 24; j++) {
            const float4* a4 = (const float4*)(AL + j * 12);
            float4 a0 = a4[0], a1 = a4[1], a2 = a4[2];
            float wj = wr[j];
            T[0] += wj * a0.x; T[1] += wj * a0.y; T[2]  += wj * a0.z; T[3]  += wj * a0.w;
            T[4] += wj * a1.x; T[5] += wj * a1.y; T[6]  += wj * a1.z; T[7]  += wj * a1.w;
            T[8] += wj * a2.x; T[9] += wj * a2.y; T[10] += wj * a2.z; T[11] += wj * a2.w;
        }
        float* pv = verts + (size_t)b * V3_ + (size_t)v * 3;
        float p0 = pv[0], p1 = pv[1], p2 = pv[2];
        pv[0] = T[0] * p0 + T[1] * p1 + T[2]  * p2 + T[3];
        pv[1] = T[4] * p0 + T[5] * p1 + T[6]  * p2 + T[7];
        pv[2] = T[8] * p0 + T[9] * p1 + T[10] * p2 + T[11];
    }
}

// ---------------------------------------------------------------------------
// K4: joints[b,jr,d] = sum_v jreg[jr,v] * verts[b,v,d]
// ---------------------------------------------------------------------------
__global__ __launch_bounds__(256) void k_joints(const float* __restrict__ jreg,
                                                const float* __restrict__ verts,
                                                float* __restrict__ joints)
{
    const int tid = threadIdx.x;
    const int b0 = blockIdx.x * 4;
    const int jr0 = blockIdx.y * 8;
    float acc[96];
#pragma unroll
    for (int c = 0; c < 96; c++) acc[c] = 0.f;

    for (int v = tid; v < V_; v += 256) {
        float jr[8];
#pragma unroll
        for (int q = 0; q < 8; q++) {
            int j = jr0 + q;
            jr[q] = (j < NJR_) ? jreg[(size_t)j * V_ + v] : 0.f;
        }
#pragma unroll
        for (int i = 0; i < 4; i++) {
            const float* pv = verts + (size_t)(b0 + i) * V3_ + (size_t)v * 3;
            float p0 = pv[0], p1 = pv[1], p2 = pv[2];
#pragma unroll
            for (int q = 0; q < 8; q++) {
                acc[q * 12 + i * 3 + 0] += jr[q] * p0;
                acc[q * 12 + i * 3 + 1] += jr[q] * p1;
                acc[q * 12 + i * 3 + 2] += jr[q] * p2;
            }
        }
    }
#pragma unroll
    for (int c = 0; c < 96; c++) {
        float s = acc[c];
#pragma unroll
        for (int off = 32; off > 0; off >>= 1) s += __shfl_xor(s, off);
        acc[c] = s;
    }
    __shared__ float red[4][96];
    const int wv = tid >> 6, ln = tid & 63;
    if (ln == 0) {
#pragma unroll
        for (int c = 0; c < 96; c++) red[wv][c] = acc[c];
    }
    __syncthreads();
    if (tid < 96) {
        float s = red[0][tid] + red[1][tid] + red[2][tid] + red[3][tid];
        int q = tid / 12, rem = tid % 12, i = rem / 3, d = rem % 3;
        int j = jr0 + q;
        if (j < NJR_) joints[(size_t)(b0 + i) * (NJR_ * 3) + j * 3 + d] = s;
    }
}

extern "C" void kernel_launch(void* const* d_in, const int* in_sizes, int n_in,
                              void* d_out, int out_size, void* d_ws, size_t ws_size,
                              hipStream_t stream)
{
    const float* beta  = (const float*)d_in[0];
    const float* theta = (const float*)d_in[1];
    const float* vtm   = (const float*)d_in[2];
    const float* sd    = (const float*)d_in[3];
    const float* pd    = (const float*)d_in[4];
    const float* JR    = (const float*)d_in[5];
    const float* jreg  = (const float*)d_in[6];
    const float* wts   = (const float*)d_in[7];  // batch-broadcast: slice [0]

    float* out = (float*)d_out;
    float* ws  = (float*)d_ws;
    float* Jst = ws + JST_OFF;
    float* cg  = ws + CG_OFF;
    float* A   = ws + A_OFF;
    float* verts  = out;
    float* joints = out + (size_t)B_ * V3_;

    hipLaunchKernelGGL(k_jst,    dim3(24),      dim3(256), 0, stream, JR, vtm, sd, Jst);
    hipLaunchKernelGGL(k_chain,  dim3(8),       dim3(32),  0, stream, beta, theta, Jst, cg, A);
    hipLaunchKernelGGL(k_vposed, dim3(162, 8),  dim3(256), 0, stream, cg, vtm, sd, pd, verts);
    hipLaunchKernelGGL(k_skin,   dim3(14, 256), dim3(256), 0, stream, wts, A, verts);
    hipLaunchKernelGGL(k_joints, dim3(64, 6),   dim3(256), 0, stream, jreg, verts, joints);
}